// Round 7
// baseline (658.333 us; speedup 1.0000x reference)
//
#include <hip/hip_runtime.h>

#define LRC 0.01f
#define LSEQ 4096
#define HIDDIM 128

typedef unsigned int u32x2 __attribute__((ext_vector_type(2)));

// x += row_ror(x, N) : after rors {8,4,2,1} every lane holds its 16-row's sum.
#define RORADD(x, ctrl)                                                      \
  x += __int_as_float(__builtin_amdgcn_update_dpp(                           \
      0, __float_as_int(x), (ctrl), 0xf, 0xf, true))

// 4 concurrent 64-lane sums, ALL-LANES result, row-mapped:
// row r (lanes 16r..16r+15) all hold sum(x_{sig(r)}), sig = [0,2,1,3].
__device__ __forceinline__ float allred4(float x0, float x1, float x2,
                                         float x3) {
  u32x2 s1 = __builtin_amdgcn_permlane32_swap(__float_as_uint(x0),
                                              __float_as_uint(x1), false, false);
  float z01 = __uint_as_float(s1.x) + __uint_as_float(s1.y);
  u32x2 s2 = __builtin_amdgcn_permlane32_swap(__float_as_uint(x2),
                                              __float_as_uint(x3), false, false);
  float z23 = __uint_as_float(s2.x) + __uint_as_float(s2.y);
  u32x2 s3 = __builtin_amdgcn_permlane16_swap(__float_as_uint(z01),
                                              __float_as_uint(z23), false, false);
  float y = __uint_as_float(s3.x) + __uint_as_float(s3.y);
  RORADD(y, 0x128);
  RORADD(y, 0x124);
  RORADD(y, 0x122);
  RORADD(y, 0x121);
  return y;
}

// 64-lane sum, result uniform across ALL lanes.
__device__ __forceinline__ float allred1(float x) {
  u32x2 s1 = __builtin_amdgcn_permlane32_swap(__float_as_uint(x),
                                              __float_as_uint(x), false, false);
  float z = __uint_as_float(s1.x) + __uint_as_float(s1.y);
  u32x2 s2 = __builtin_amdgcn_permlane16_swap(__float_as_uint(z),
                                              __float_as_uint(z), false, false);
  z = __uint_as_float(s2.x) + __uint_as_float(s2.y);
  RORADD(z, 0x128);
  RORADD(z, 0x124);
  RORADD(z, 0x122);
  RORADD(z, 0x121);
  return z;
}

// Read the row-mapped value for inner unit i (sig is an involution:
// value i lives on rows with sig(row)=i, i.e. lane 16*sig(i)).
#define RL(x, L) __int_as_float(__builtin_amdgcn_readlane(__float_as_int(x), (L)))

__global__ __launch_bounds__(64) void ttt_kernel(
    const float* __restrict__ h, const float* __restrict__ W1,
    const float* __restrict__ b1, const float* __restrict__ W2,
    const float* __restrict__ b2, float* __restrict__ out) {
  const int b = blockIdx.x;
  const int lane = threadIdx.x;  // 0..63
  const int d0 = lane * 2;       // lane owns hidden dims d0, d0+1
  const float* __restrict__ hb = h + (size_t)b * (LSEQ * HIDDIM);
  const int g = lane >> 4;
  const int sig = ((g & 1) << 1) | (g >> 1);  // row g holds inner unit sig(g)

  // ---- weight state in registers ----
  float2 w1v[8];  // (W1[i][d0], W1[i][d0+1])
  float2 w2v[8];  // (W2[d0][i], W2[d0+1][i])
#pragma unroll
  for (int i = 0; i < 8; ++i) {
    w1v[i] = *reinterpret_cast<const float2*>(W1 + i * HIDDIM + d0);
    w2v[i].x = W2[(size_t)d0 * 8 + i];
    w2v[i].y = W2[(size_t)(d0 + 1) * 8 + i];
  }
  float2 b2v = *reinterpret_cast<const float2*>(b2 + d0);
  float b1A = b1[sig];      // row-mapped b1 state (i = sig(g))
  float b1B = b1[4 + sig];  // (i = 4 + sig(g))

  const float cneg = -(LRC * 2.0f / (float)HIDDIM);

  // ---- 3-slot k/v rotation, prefetch distance ~2.5 steps ----
  const float* pf = hb + d0;
  float2 kA = *reinterpret_cast<const float2*>(pf + 0 * HIDDIM);
  float2 vA = *reinterpret_cast<const float2*>(pf + 1 * HIDDIM);
  float2 kB = *reinterpret_cast<const float2*>(pf + 2 * HIDDIM);
  float2 vB = *reinterpret_cast<const float2*>(pf + 3 * HIDDIM);
  float2 kC = *reinterpret_cast<const float2*>(pf + 4 * HIDDIM);
  float2 vC = *reinterpret_cast<const float2*>(pf + 5 * HIDDIM);
  pf += 6 * HIDDIM;

  // ---- a(0) = W1 k(0) + b1, row-mapped ----
  float aA, aB;
  {
    float pa[8];
#pragma unroll
    for (int i = 0; i < 8; ++i) pa[i] = fmaf(w1v[i].x, kA.x, w1v[i].y * kA.y);
    aA = allred4(pa[0], pa[1], pa[2], pa[3]) + b1A;
    aB = allred4(pa[4], pa[5], pa[6], pa[7]) + b1B;
  }

  // One SGD step s. In: a(s) row-mapped (aA,aB), k(s), v(s), k(s+1).
  // Out: updated weights, a(s+1) via rank-1 factorization:
  //   a(s+1) = red(W1(s) k(s+1)) + da(s)*(red(k(s)·k(s+1)) + 1) + b1(s)
  auto STEP = [&](float2 k, float2 v, float2 kn) {
    float rA = fmaxf(aA, 0.0f), rB = fmaxf(aB, 0.0f);
    // broadcast r_i to SGPRs (value i lives at lane 16*sig(i))
    float r0 = RL(rA, 0), r1 = RL(rA, 32), r2 = RL(rA, 16), r3 = RL(rA, 48);
    float r4 = RL(rB, 0), r5 = RL(rB, 32), r6 = RL(rB, 16), r7 = RL(rB, 48);
    // pred = W2 r + b2 (two partial accumulators)
    float2 p0, p1;
    p0.x = fmaf(w2v[0].x, r0, b2v.x);
    p0.y = fmaf(w2v[0].y, r0, b2v.y);
    p1.x = w2v[1].x * r1;
    p1.y = w2v[1].y * r1;
    p0.x = fmaf(w2v[2].x, r2, p0.x);
    p0.y = fmaf(w2v[2].y, r2, p0.y);
    p1.x = fmaf(w2v[3].x, r3, p1.x);
    p1.y = fmaf(w2v[3].y, r3, p1.y);
    p0.x = fmaf(w2v[4].x, r4, p0.x);
    p0.y = fmaf(w2v[4].y, r4, p0.y);
    p1.x = fmaf(w2v[5].x, r5, p1.x);
    p1.y = fmaf(w2v[5].y, r5, p1.y);
    p0.x = fmaf(w2v[6].x, r6, p0.x);
    p0.y = fmaf(w2v[6].y, r6, p0.y);
    p1.x = fmaf(w2v[7].x, r7, p1.x);
    p1.y = fmaf(w2v[7].y, r7, p1.y);
    float2 gl;
    gl.x = (p0.x + p1.x - v.x) * cneg;
    gl.y = (p0.y + p1.y - v.y) * cneg;
    // dp partials from OLD w2 -> row-mapped reductions -> mask
    float dp[8];
#pragma unroll
    for (int i = 0; i < 8; ++i) dp[i] = fmaf(w2v[i].x, gl.x, w2v[i].y * gl.y);
    float zA = allred4(dp[0], dp[1], dp[2], dp[3]);
    float zB = allred4(dp[4], dp[5], dp[6], dp[7]);
    float daA = (aA > 0.0f) ? zA : 0.0f;  // == -lr * da_ref, row-mapped
    float daB = (aB > 0.0f) ? zB : 0.0f;
    // next-step a ingredients with OLD w1: tp = red(W1 k(s+1)), kk
    float tp[8];
#pragma unroll
    for (int i = 0; i < 8; ++i) tp[i] = fmaf(w1v[i].x, kn.x, w1v[i].y * kn.y);
    float tA = allred4(tp[0], tp[1], tp[2], tp[3]);
    float tB = allred4(tp[4], tp[5], tp[6], tp[7]);
    float kkp1 = allred1(fmaf(k.x, kn.x, k.y * kn.y)) + 1.0f;
    // w2 / b2 update (uses SGPR r_i)
    w2v[0].x = fmaf(gl.x, r0, w2v[0].x); w2v[0].y = fmaf(gl.y, r0, w2v[0].y);
    w2v[1].x = fmaf(gl.x, r1, w2v[1].x); w2v[1].y = fmaf(gl.y, r1, w2v[1].y);
    w2v[2].x = fmaf(gl.x, r2, w2v[2].x); w2v[2].y = fmaf(gl.y, r2, w2v[2].y);
    w2v[3].x = fmaf(gl.x, r3, w2v[3].x); w2v[3].y = fmaf(gl.y, r3, w2v[3].y);
    w2v[4].x = fmaf(gl.x, r4, w2v[4].x); w2v[4].y = fmaf(gl.y, r4, w2v[4].y);
    w2v[5].x = fmaf(gl.x, r5, w2v[5].x); w2v[5].y = fmaf(gl.y, r5, w2v[5].y);
    w2v[6].x = fmaf(gl.x, r6, w2v[6].x); w2v[6].y = fmaf(gl.y, r6, w2v[6].y);
    w2v[7].x = fmaf(gl.x, r7, w2v[7].x); w2v[7].y = fmaf(gl.y, r7, w2v[7].y);
    b2v.x += gl.x;
    b2v.y += gl.y;
    // W1 update: broadcast da_i to SGPRs, rank-1 add
    float e0 = RL(daA, 0), e1 = RL(daA, 32), e2 = RL(daA, 16), e3 = RL(daA, 48);
    float e4 = RL(daB, 0), e5 = RL(daB, 32), e6 = RL(daB, 16), e7 = RL(daB, 48);
    w1v[0].x = fmaf(e0, k.x, w1v[0].x); w1v[0].y = fmaf(e0, k.y, w1v[0].y);
    w1v[1].x = fmaf(e1, k.x, w1v[1].x); w1v[1].y = fmaf(e1, k.y, w1v[1].y);
    w1v[2].x = fmaf(e2, k.x, w1v[2].x); w1v[2].y = fmaf(e2, k.y, w1v[2].y);
    w1v[3].x = fmaf(e3, k.x, w1v[3].x); w1v[3].y = fmaf(e3, k.y, w1v[3].y);
    w1v[4].x = fmaf(e4, k.x, w1v[4].x); w1v[4].y = fmaf(e4, k.y, w1v[4].y);
    w1v[5].x = fmaf(e5, k.x, w1v[5].x); w1v[5].y = fmaf(e5, k.y, w1v[5].y);
    w1v[6].x = fmaf(e6, k.x, w1v[6].x); w1v[6].y = fmaf(e6, k.y, w1v[6].y);
    w1v[7].x = fmaf(e7, k.x, w1v[7].x); w1v[7].y = fmaf(e7, k.y, w1v[7].y);
    // a(s+1), b1 update (row-mapped; uses OLD b1)
    aA = fmaf(daA, kkp1, tA + b1A);
    aB = fmaf(daB, kkp1, tB + b1B);
    b1A += daA;
    b1B += daB;
  };

  // steps 0..2042: 681 iterations x 3 (3-slot rotation)
  for (int it = 0; it < 681; ++it) {
    {
      float2 k = kA, v = vA, kn = kB;
      kA = *reinterpret_cast<const float2*>(pf + 0 * HIDDIM);
      vA = *reinterpret_cast<const float2*>(pf + 1 * HIDDIM);
      STEP(k, v, kn);  // s = 3it
    }
    {
      float2 k = kB, v = vB, kn = kC;
      kB = *reinterpret_cast<const float2*>(pf + 2 * HIDDIM);
      vB = *reinterpret_cast<const float2*>(pf + 3 * HIDDIM);
      STEP(k, v, kn);  // s = 3it+1
    }
    {
      float2 k = kC, v = vC, kn = kA;  // kn = freshly loaded k(3it+3)
      kC = *reinterpret_cast<const float2*>(pf + 4 * HIDDIM);
      vC = *reinterpret_cast<const float2*>(pf + 5 * HIDDIM);
      STEP(k, v, kn);  // s = 3it+2
    }
    pf += 6 * HIDDIM;
  }

  // tail: pf at row 4092. steps 2043..2046, then final predict with row 4095.
  float2 kD = *reinterpret_cast<const float2*>(pf + 0 * HIDDIM);  // row 4092
  float2 vD = *reinterpret_cast<const float2*>(pf + 1 * HIDDIM);  // row 4093
  float2 kE = *reinterpret_cast<const float2*>(pf + 2 * HIDDIM);  // row 4094
  float2 xv = *reinterpret_cast<const float2*>(pf + 3 * HIDDIM);  // row 4095
  STEP(kA, vA, kB);  // 2043 (rows 4086/4087)
  STEP(kB, vB, kC);  // 2044
  STEP(kC, vC, kD);  // 2045
  STEP(kD, vD, kE);  // 2046 (kn only feeds a discarded a)

  // ---- final prediction with x = h[b, L-1] ----
  {
    float pa[8];
#pragma unroll
    for (int i = 0; i < 8; ++i) pa[i] = fmaf(w1v[i].x, xv.x, w1v[i].y * xv.y);
    float fA = fmaxf(allred4(pa[0], pa[1], pa[2], pa[3]) + b1A, 0.0f);
    float fB = fmaxf(allred4(pa[4], pa[5], pa[6], pa[7]) + b1B, 0.0f);
    float r0 = RL(fA, 0), r1 = RL(fA, 32), r2 = RL(fA, 16), r3 = RL(fA, 48);
    float r4 = RL(fB, 0), r5 = RL(fB, 32), r6 = RL(fB, 16), r7 = RL(fB, 48);
    float2 o = b2v;
    o.x = fmaf(w2v[0].x, r0, o.x); o.y = fmaf(w2v[0].y, r0, o.y);
    o.x = fmaf(w2v[1].x, r1, o.x); o.y = fmaf(w2v[1].y, r1, o.y);
    o.x = fmaf(w2v[2].x, r2, o.x); o.y = fmaf(w2v[2].y, r2, o.y);
    o.x = fmaf(w2v[3].x, r3, o.x); o.y = fmaf(w2v[3].y, r3, o.y);
    o.x = fmaf(w2v[4].x, r4, o.x); o.y = fmaf(w2v[4].y, r4, o.y);
    o.x = fmaf(w2v[5].x, r5, o.x); o.y = fmaf(w2v[5].y, r5, o.y);
    o.x = fmaf(w2v[6].x, r6, o.x); o.y = fmaf(w2v[6].y, r6, o.y);
    o.x = fmaf(w2v[7].x, r7, o.x); o.y = fmaf(w2v[7].y, r7, o.y);
    *reinterpret_cast<float2*>(out + (size_t)b * HIDDIM + d0) = o;
  }
}

extern "C" void kernel_launch(void* const* d_in, const int* in_sizes, int n_in,
                              void* d_out, int out_size, void* d_ws, size_t ws_size,
                              hipStream_t stream) {
  const float* h  = (const float*)d_in[0];
  const float* W1 = (const float*)d_in[1];
  const float* b1 = (const float*)d_in[2];
  const float* W2 = (const float*)d_in[3];
  const float* b2 = (const float*)d_in[4];
  float* out = (float*)d_out;
  ttt_kernel<<<256, 64, 0, stream>>>(h, W1, b1, W2, b2, out);
}